// Round 15
// baseline (58.027 us; speedup 1.0000x reference)
//
#include <hip/hip_runtime.h>

// Problem constants (from the reference):
//   B=32768 batch, T=256 trees, D=10 depth, F=512 features, C=1 leaf dim
constexpr int kB = 32768;
constexpr int kT = 256;
constexpr int kD = 10;
constexpr int kF = 512;
constexpr int kLvlPad = kT << (kD - 1); // 131072
constexpr int kLevels = kD - 1;         // 9

constexpr int kRows    = 64;             // batch rows per block = wave size
constexpr int kSlots   = 16;             // tree slots (wave-uniform tree)
constexpr int kTrees   = 256;            // trees per block = ALL trees
constexpr int kChains  = 16;             // chains per thread
constexpr int kThreads = 1024;           // 64 rows x 16 slots
constexpr int kXPad    = 516;            // padded x row stride (floats)
constexpr int kOPad    = kTrees + 1;     // outs stride 257

// Pair-table record counts / offsets (16B records in d_ws) — R12 layout.
// Pair (i,i+1) table indexed by the GLOBAL level-i index (width T*2^i):
//   {u32 n_top|nL<<9|nR<<18, f32 b_top, f32 bL, f32 bR}  (node idx < 512)
// One dwordx4 gather advances TWO levels. Fused record (level 9 + leaf):
//   {n9, b9, leaf[2j], leaf[2j+1]} indexed by global level-9 index.
constexpr int kP1 = kT * 2;      // 512
constexpr int kP3 = kT * 8;      // 2048
constexpr int kP5 = kT * 32;     // 8192
constexpr int kP7 = kT * 128;    // 32768
constexpr int kFU = kT * 512;    // 131072
constexpr int kO1 = 0;
constexpr int kO3 = kO1 + kP1;   // 512
constexpr int kO5 = kO3 + kP3;   // 2560
constexpr int kO7 = kO5 + kP5;   // 10752
constexpr int kOF = kO7 + kP7;   // 43520
constexpr int kTotalRecs = kOF + kFU; // 174592
constexpr size_t kWsBytes = (size_t)kTotalRecs * 16; // 2,793,472 B

// Build all pair tables + fused table in one launch.
__global__ __launch_bounds__(256)
void prep_kernel(const int* __restrict__ nodes, const float* __restrict__ biases,
                 const float* __restrict__ leaf_nodes, int4* __restrict__ ws)
{
    int idx = blockIdx.x * 256 + threadIdx.x;
    if (idx < kOF) {
        int i, base;
        if      (idx < kO3) { i = 1; base = kO1; }
        else if (idx < kO5) { i = 3; base = kO3; }
        else if (idx < kO7) { i = 5; base = kO5; }
        else                { i = 7; base = kO7; }
        int j = idx - base;                      // global index into level i
        const int*   nt = nodes  + (size_t)(i - 1) * kLvlPad; // level i
        const float* bt = biases + (size_t)(i - 1) * kLvlPad;
        const int*   nc = nodes  + (size_t)i * kLvlPad;       // level i+1
        const float* bc = biases + (size_t)i * kLvlPad;
        unsigned int pk = (unsigned int)nt[j]
                        | ((unsigned int)nc[2 * j]     << 9)
                        | ((unsigned int)nc[2 * j + 1] << 18);
        ws[idx] = make_int4((int)pk, __float_as_int(bt[j]),
                            __float_as_int(bc[2 * j]),
                            __float_as_int(bc[2 * j + 1]));
    } else if (idx < kTotalRecs) {
        int j = idx - kOF;                       // global index into level 9
        const int   n9 = nodes [(size_t)(kD - 2) * kLvlPad + j];
        const float b9 = biases[(size_t)(kD - 2) * kLvlPad + j];
        ws[idx] = make_int4(n9, __float_as_int(b9),
                            __float_as_int(leaf_nodes[2 * j]),
                            __float_as_int(leaf_nodes[2 * j + 1]));
    }
}

// R14 with ONE change: 64 rows per block — ALL 64 lanes of a wave walk the
// SAME tree (one batch row each), so every deep gather's 64 draws share
// lines within one tree window: expected distinct lines/wave-gather
// FU 57->50, P7 41->28, P5 16->8 => total L2 lookups -26%. The occupancy
// cost (132KB LDS -> 1 block/CU, 16 waves) is compensated by 16 chains per
// thread: outstanding gathers/CU = 16 waves x 16 = 256, same as R14's
// 32 x 8. launch_bounds(1024,4) forces VGPR<=128 so all 16 waves of the
// block are resident. Chain: root -> P1 -> P3 -> P5 -> P7 -> FU = 6
// dependent gathers. xs reused as output staging.
__global__ __launch_bounds__(kThreads, 4)
void traverse_pair_kernel(const float* __restrict__ x,
                          const int* __restrict__ root_nodes,
                          const float* __restrict__ root_biases,
                          const int4* __restrict__ ws,
                          float* __restrict__ out)
{
    __shared__ float xs[kRows][kXPad];        // 132,096 B (reused for outs)
    float* outs = &xs[0][0];                  // alias: [kRows][kOPad]

    const int b0  = blockIdx.x * kRows;
    const int tid = threadIdx.x;

    // Stage 64 x rows (8192 float4), coalesced.
    {
        const float4* xg = reinterpret_cast<const float4*>(x + (size_t)b0 * kF);
#pragma unroll
        for (int k = 0; k < 8; ++k) {
            int j = tid + k * kThreads;   // 0..8191
            int r = j >> 7;
            int c = j & 127;
            float4 v = xg[(size_t)r * (kF / 4) + c];
            *reinterpret_cast<float4*>(&xs[r][c * 4]) = v;
        }
    }
    __syncthreads();

    const int r    = tid & (kRows - 1);  // row = lane (wave-uniform tree)
    const int slot = tid >> 6;           // 0..15
    const float* __restrict__ xrow = xs[r];

    int p[kChains];
#pragma unroll
    for (int c = 0; c < kChains; ++c) {
        int t = slot + kSlots * c;       // 16 chains cover all 256 trees
        p[c] = 2 * t + (xrow[root_nodes[t]] <= root_biases[t] ? 1 : 0);
    }

    const int4* __restrict__ P1 = ws + kO1;
    const int4* __restrict__ P3 = ws + kO3;
    const int4* __restrict__ P5 = ws + kO5;
    const int4* __restrict__ P7 = ws + kO7;
    const int4* __restrict__ FU = ws + kOF;

    // Pair step: one 16B gather advances two levels (proven R12 form).
#define PAIR_STEP(TBL)                                                        \
    {                                                                         \
        int4 rec[kChains];                                                    \
        _Pragma("unroll")                                                     \
        for (int c = 0; c < kChains; ++c) rec[c] = TBL[p[c]];                 \
        _Pragma("unroll")                                                     \
        for (int c = 0; c < kChains; ++c) {                                   \
            unsigned int n = (unsigned int)rec[c].x;                          \
            int c0 = xrow[n & 511u] <= __int_as_float(rec[c].y) ? 1 : 0;      \
            int nc = c0 ? (int)((n >> 18) & 511u) : (int)((n >> 9) & 511u);   \
            int bb = c0 ? rec[c].w : rec[c].z;                                \
            int c1 = xrow[nc] <= __int_as_float(bb) ? 1 : 0;                  \
            p[c] = 4 * p[c] + 2 * c0 + c1;                                    \
        }                                                                     \
    }

    PAIR_STEP(P1)   // levels 1,2
    PAIR_STEP(P3)   // levels 3,4
    PAIR_STEP(P5)   // levels 5,6
    PAIR_STEP(P7)   // levels 7,8
#undef PAIR_STEP

    // Fused level 9 + leaf: one 16B gather finishes each tree.
    float leaf[kChains];
    {
        int4 rec[kChains];
#pragma unroll
        for (int c = 0; c < kChains; ++c) rec[c] = FU[p[c]];
#pragma unroll
        for (int c = 0; c < kChains; ++c) {
            leaf[c] = __int_as_float(
                xrow[rec[c].x] <= __int_as_float(rec[c].y) ? rec[c].w
                                                           : rec[c].z);
        }
    }

    // xs is dead now; reuse it as the output staging buffer.
    __syncthreads();
#pragma unroll
    for (int c = 0; c < kChains; ++c)
        outs[r * kOPad + slot + kSlots * c] = leaf[c];
    __syncthreads();

#pragma unroll
    for (int k = 0; k < 16; ++k) {
        int j    = tid + k * kThreads;  // 0..16383
        int orow = j >> 8;              // 0..63
        int ocol = j & 255;             // 0..255
        __builtin_nontemporal_store(outs[orow * kOPad + ocol],
                                    &out[(size_t)(b0 + orow) * kT + ocol]);
    }
}

// Fallback (no workspace): straightforward per-level walk.
__global__ __launch_bounds__(512)
void traverse_plain_kernel(const float* __restrict__ x,
                           const int* __restrict__ root_nodes,
                           const float* __restrict__ root_biases,
                           const int* __restrict__ nodes,
                           const float* __restrict__ biases,
                           const float* __restrict__ leaf_nodes,
                           float* __restrict__ out)
{
    __shared__ float xs[16][kXPad];
    __shared__ float outs[16][65];

    const int b0  = blockIdx.x * 16;
    const int t0  = blockIdx.y * 64;
    const int tid = threadIdx.x;

    {
        const float4* xg = reinterpret_cast<const float4*>(x + (size_t)b0 * kF);
#pragma unroll
        for (int k = 0; k < 4; ++k) {
            int j = tid + k * 512;
            int r = j >> 7;
            int c = j & 127;
            float4 v = xg[(size_t)r * (kF / 4) + c];
            *reinterpret_cast<float4*>(&xs[r][c * 4]) = v;
        }
    }
    __syncthreads();

    const int r  = tid & 15;
    const int tt = tid >> 4;
    const int tA = t0 + tt;
    const int tB = t0 + tt + 32;
    const float* __restrict__ xrow = xs[r];

    int pA = 2 * tA + (xrow[root_nodes[tA]] <= root_biases[tA] ? 1 : 0);
    int pB = 2 * tB + (xrow[root_nodes[tB]] <= root_biases[tB] ? 1 : 0);

#pragma unroll
    for (int i = 1; i < kD; ++i) {
        const int*   ln = nodes  + (size_t)(i - 1) * kLvlPad;
        const float* lb = biases + (size_t)(i - 1) * kLvlPad;
        int   nA = ln[pA], nB = ln[pB];
        float bA = lb[pA], bB = lb[pB];
        pA = 2 * pA + (xrow[nA] <= bA ? 1 : 0);
        pB = 2 * pB + (xrow[nB] <= bB ? 1 : 0);
    }

    outs[r][tt]      = leaf_nodes[pA];
    outs[r][tt + 32] = leaf_nodes[pB];
    __syncthreads();

#pragma unroll
    for (int k = 0; k < 2; ++k) {
        int j    = tid + k * 512;
        int orow = j >> 6;
        int ocol = j & 63;
        __builtin_nontemporal_store(outs[orow][ocol],
                                    &out[(size_t)(b0 + orow) * kT + t0 + ocol]);
    }
}

extern "C" void kernel_launch(void* const* d_in, const int* in_sizes, int n_in,
                              void* d_out, int out_size, void* d_ws, size_t ws_size,
                              hipStream_t stream) {
    const float* x           = (const float*)d_in[0];
    const int*   root_nodes  = (const int*)d_in[1];
    const float* root_biases = (const float*)d_in[2];
    const int*   nodes       = (const int*)d_in[3];
    const float* biases      = (const float*)d_in[4];
    const float* leaf_nodes  = (const float*)d_in[5];
    float*       out         = (float*)d_out;

    if (ws_size >= kWsBytes) {
        prep_kernel<<<(kTotalRecs + 255) / 256, 256, 0, stream>>>(
            nodes, biases, leaf_nodes, (int4*)d_ws);
        const int nblocks = kB / kRows; // 512
        traverse_pair_kernel<<<nblocks, kThreads, 0, stream>>>(
            x, root_nodes, root_biases, (const int4*)d_ws, out);
    } else {
        dim3 grid(kB / 16, kT / 64); // (2048, 4)
        traverse_plain_kernel<<<grid, 512, 0, stream>>>(
            x, root_nodes, root_biases, nodes, biases, leaf_nodes, out);
    }
}